// Round 15
// baseline (150.071 us; speedup 1.0000x reference)
//
#include <hip/hip_runtime.h>

// KAN conv feature extractor, fully fused: one workgroup (256 thr) per batch element.
// conv1 3x3 (1->5) + maxpool2 -> conv2 5x5 (5->5) -> conv3 3x3 (5->2) -> FC(98->200)
// All three convs on MFMA (v_mfma_f32_16x16x32_f16). Activation records in LDS;
// K/M-pads always multiply ZERO weight columns against FINITE fp16 data (never 0*Inf).
// R15 = R14 (77.1us) + instruction diet round 2 (kernel is CU-aggregate issue-bound;
// only total issued instructions move it):
//  (a) t2/t3 channel stride 10 -> 12 halves: record base (pp*72 + c*12) is 8B-aligned
//      -> write_rec10a = 3 LDS stores (b64,b64,b32) instead of 5 dwords; w2col/w3col
//      K-map becomes c*12+f with f in {10,11} zero-weight pads (A-reads unchanged).
//  (b) FC as uint2 pairs: fcwQ[25][200] uint2 (4 cols per load) + h3 read as uint2
//      -> 25 x {dwordx2, ds b64, 2 dot2} vs 49 x {dword, b32, dot2}. h3h[98..99]
//      zeroed (stale part2 bits could be NaN-as-fp16 x pad weight).
//  (c) kan_prep: 64 blocks, coalesced fcwQ build.

typedef _Float16 h2 __attribute__((ext_vector_type(2)));
typedef _Float16 f16x8 __attribute__((ext_vector_type(8)));
typedef float f32x4 __attribute__((ext_vector_type(4)));
typedef unsigned int uint_t;
typedef unsigned long long u64;

__device__ __forceinline__ h2 as_h2(uint_t u) { union { uint_t u; h2 h; } c; c.u = u; return c.h; }
__device__ __forceinline__ uint_t pk(float a, float b) {
    h2 v; v[0] = (_Float16)a; v[1] = (_Float16)b;
    union { h2 h; uint_t u; } c; c.h = v; return c.u;
}

__device__ __forceinline__ float fdot2f(h2 a, h2 b, float c) {
#if __has_builtin(__builtin_amdgcn_fdot2)
    return __builtin_amdgcn_fdot2(a, b, c, false);
#else
    return c + (float)a[0] * (float)b[0] + (float)a[1] * (float)b[1];
#endif
}

__device__ __forceinline__ float silu_f(float v) {
    return v / (1.0f + __expf(-v));
}

// Record words for value v: halves [silu, b0..b7, 0] as R0(4h), R1(4h), R2(2h).
// Uniform-knot cubic B-spline, grid[j] = (j-3)*0.4 - 1; only 4 bases nonzero:
// cell c = floor((v+2.2)/0.4), u = frac; bases j=c-3..c get
// {(1-u)^3, 3u^3-6u^2+4, -3u^3+3u^2+3u+1, u^3}/6 (branchless 128-bit funnel shift).
struct RecW { u64 R0, R1; uint_t R2; };
__device__ __forceinline__ RecW rec_words(float v) {
    float s  = silu_f(v);
    float t  = (v + 2.2f) * 2.5f;
    float cf = floorf(t);
    int   c  = (int)cf;
    float u  = t - cf;
    float u2 = u * u, u3 = u2 * u;
    float w  = 1.0f - u;
    const float k6 = 0.16666667f;
    float n0 = k6 * u3;
    float n1 = k6 * (-3.0f * u3 + 3.0f * u2 + 3.0f * u + 1.0f);
    float n2 = k6 * (3.0f * u3 - 6.0f * u2 + 4.0f);
    float n3 = k6 * (w * w * w);
    u64 H = ((u64)pk(n1, n0) << 32) | (u64)pk(n3, n2);   // halves [n3,n2,n1,n0]
    if ((unsigned)c > 10u) H = 0;                        // outside [-2.2,2.2): zero bases
    int cc = c < 0 ? 0 : (c > 10 ? 10 : c);
    int L  = cc * 16 - 48;                               // window shift, mult of 16
    u64 sl_lo = (L < 64) ? (H << (L & 63)) : 0;
    u64 hi_a  = (L == 0) ? 0 : (H >> ((64 - L) & 63));
    u64 hi_b  = H << ((L - 64) & 63);
    u64 sl_hi = (L < 64) ? hi_a : hi_b;
    u64 sr    = H >> ((-L) & 63);
    u64 B0 = (L >= 0) ? sl_lo : sr;                      // window halves 0..3
    u64 B1 = (L >= 0) ? sl_hi : 0;                       // window halves 4..7
    RecW r;
    r.R0 = (B0 << 16) | (u64)pk(s, 0.0f);                // [silu, b0, b1, b2]
    r.R1 = (B0 >> 48) | (B1 << 16);                      // [b3, b4, b5, b6]
    r.R2 = (uint_t)(B1 >> 48);                           // [b7, 0]
    return r;
}

// 16-half record with XOR-swizzled 16B chunks (t1).
__device__ __forceinline__ void write_rec16s(_Float16* p, int off, float v) {
    RecW rw = rec_words(v);
    uint4 lo, hi;
    lo.x = (uint_t)rw.R0; lo.y = (uint_t)(rw.R0 >> 32);
    lo.z = (uint_t)rw.R1; lo.w = (uint_t)(rw.R1 >> 32);
    hi.x = rw.R2; hi.y = 0; hi.z = 0; hi.w = 0;
    *(uint4*)(p + off)       = lo;                       // halves 0-7
    *(uint4*)(p + (8 ^ off)) = hi;                       // halves 8-15
}

// 10-half record at an 8B-aligned base (c*12 channel stride): 3 stores.
__device__ __forceinline__ void write_rec10a(_Float16* p, float v) {
    RecW rw = rec_words(v);
    uint2 w0, w1;
    w0.x = (uint_t)rw.R0; w0.y = (uint_t)(rw.R0 >> 32);
    w1.x = (uint_t)rw.R1; w1.y = (uint_t)(rw.R1 >> 32);
    *(uint2*)(p)      = w0;                              // halves 0-3
    *(uint2*)(p + 4)  = w1;                              // halves 4-7
    *(uint_t*)(p + 8) = rw.R2;                           // halves 8-9
}

// d_ws layout (bytes):
//   [0)      fcwQ : u32 [25][200][2] FC weight quads: uint2 element (w,o) holds
//                   cols 4w..4w+3 of W[o][:]; cols >=98 are 0
//   [40000)  w1col: fp16 [6][160]  conv1 K-major cols (col5 zero; 10 recs x 16h,
//                                  rec t<9, f<9 real; else 0)
//   [41920)  w2col: fp16 [6][1600] conv2 tap-major cols [tap(di*5+dj)][64h]:
//                                  k -> (c=k/12, f=k%12); c>=5 or f>=9 -> 0
//   [61120)  w3col: fp16 [6][576]  conv3 tap-major cols, same c*12+f K-map, cols 2-5 zero
#define FCWQ_BYTE_OFF   0
#define W1COL_BYTE_OFF  40000
#define W2COL_BYTE_OFF  41920
#define W3COL_BYTE_OFF  61120

__global__ __launch_bounds__(256) void kan_prep(
    const float* __restrict__ wb1, const float* __restrict__ ws1,
    const float* __restrict__ wb2, const float* __restrict__ ws2,
    const float* __restrict__ wb3, const float* __restrict__ ws3,
    const float* __restrict__ fcw, uint_t* __restrict__ fcwQ,
    _Float16* __restrict__ w1col, _Float16* __restrict__ w2col,
    _Float16* __restrict__ w3col)
{
    int gtid = blockIdx.x * 256 + threadIdx.x;
    int gstr = gridDim.x * 256;
    for (int i = gtid; i < 10000; i += gstr) {        // fcwQ u32 [25][200][2]
        int wq = i / 400, rem = i % 400;
        int o = rem >> 1, j = rem & 1;
        int c0 = 4 * wq + 2 * j;
        float v0 = (c0     < 98) ? fcw[o * 98 + c0]     : 0.f;
        float v1 = (c0 + 1 < 98) ? fcw[o * 98 + c0 + 1] : 0.f;
        fcwQ[i] = pk(v0, v1);
    }
    for (int i = gtid; i < 960; i += gstr) {          // w1col [6][160]
        int n = i / 160, k = i % 160;
        int rec = k >> 4, f = k & 15;
        float v = 0.f;
        if (n < 5 && rec < 9 && f < 9)
            v = (f == 0) ? wb1[n * 9 + rec] : ws1[(n * 9 + rec) * 8 + (f - 1)];
        w1col[i] = (_Float16)v;
    }
    for (int i = gtid; i < 9600; i += gstr) {         // w2col [6][1600], k = c*12+f
        int n = i / 1600, k2 = i % 1600;
        int tap = k2 >> 6, k = k2 & 63;
        int di = tap / 5, dj = tap % 5;
        int c = k / 12, f = k % 12;
        float v = 0.f;
        if (n < 5 && c < 5 && f < 9) {
            int r = n * 125 + c * 25 + di * 5 + dj;
            v = (f == 0) ? wb2[r] : ws2[r * 8 + (f - 1)];
        }
        w2col[i] = (_Float16)v;
    }
    for (int i = gtid; i < 3456; i += gstr) {         // w3col [6][576], k = c*12+f
        int n = i / 576, k2 = i % 576;
        int tap = k2 >> 6, k = k2 & 63;
        int di = tap / 3, dj = tap % 3;
        int c = k / 12, f = k % 12;
        float v = 0.f;
        if (n < 2 && c < 5 && f < 9) {
            int r = n * 45 + c * 9 + di * 3 + dj;
            v = (f == 0) ? wb3[r] : ws3[r * 8 + (f - 1)];
        }
        w3col[i] = (_Float16)v;
    }
}

// LDS (overlaid in time):
//   smemA fp16[12544]: t1 [784][16] (XOR-swizzled chunks) = 12544h
//                    | t2 [169 pos][72] (5c x 12h @ c*12, f<10 real) = 12168h
//                    | t3 [81 pos][72] (channel-packed, reuses t2 addresses)
//   smemB f32[1696]:   P2h fp16 [5][676] = 1690f | part2 [4w][5o][81] = 1620f
//                    | h3h fp16 [100] (aliases part2 base; part2 dead after 4b)
// Total 31872 B -> 5 WG/CU (20 waves), same geometry as R8/R14.
__global__ __launch_bounds__(256) void kan_fused(
    const float* __restrict__ x,        // [B,1,28,28]
    const _Float16* __restrict__ w1col, // [6][160]
    const _Float16* __restrict__ w2col, // [6][1600]
    const _Float16* __restrict__ w3col, // [6][576]
    const uint_t* __restrict__ fcwQ,    // [25][200][2] u32
    const float* __restrict__ fcb,      // [200]
    float* __restrict__ out)            // [B,200]
{
    __shared__ __align__(16) _Float16 smemA[12544];
    __shared__ __align__(16) float    smemB[1696];
    _Float16* P2h   = (_Float16*)smemB;  // [c][676] halves
    float*    part2 = smemB;             // [(w*5+o)*81 + pp]
    _Float16* h3h   = (_Float16*)smemB;  // [100] fp16 (after 4b)

    const int b   = blockIdx.x;
    const int tid = threadIdx.x;
    const int wv  = __builtin_amdgcn_readfirstlane(tid >> 6);  // wave id 0..3
    const int ln  = tid & 63;

    // MFMA lane decomposition
    const int m   = ln & 15;        // A row (position); C col (out ch)
    const int kb  = ln >> 4;        // k-block: lane k = kb*8 + j
    const int hr  = kb >> 1;        // conv1: record within kstep pair
    const int s8  = (kb & 1) * 8;   // conv1: half offset within record
    const int nn  = m < 5 ? m : 5;  // B column (col 5 = zeros)

    // ---- Phase 1: transform input pixels -> t1 records (swizzled) --------
#pragma unroll 1
    for (int i = tid; i < 784; i += 256)
        write_rec16s(&smemA[i * 16], (i & 4) << 1, x[b * 784 + i]);
    __syncthreads();

    // ---- Phase 2: conv1 3x3 via MFMA: M=676 (43 tiles), N=5(->16), K=160 -
    {
        f16x8 Bf[5];
#pragma unroll
        for (int ks = 0; ks < 5; ++ks)
            Bf[ks] = *(const f16x8*)(w1col + nn * 160 + ks * 32 + kb * 8);
        const int dpix[10] = {0, 1, 2, 28, 29, 30, 56, 57, 58, 0};
#pragma unroll 1
        for (int tile = wv; tile < 43; tile += 4) {
            int p = tile * 16 + m; p = p > 675 ? 675 : p;   // M-pad: clamp (finite A)
            int pix0 = (p / 26) * 28 + (p % 26);
            f32x4 acc = {0.f, 0.f, 0.f, 0.f};
#pragma unroll
            for (int ks = 0; ks < 5; ++ks) {
                int dp = hr ? dpix[2 * ks + 1] : dpix[2 * ks];
                int p2 = pix0 + dp;
                int addr = p2 * 16 + (s8 ^ ((p2 & 4) << 1));   // match writer swizzle
                f16x8 av = *(const f16x8*)(smemA + addr);
                acc = __builtin_amdgcn_mfma_f32_16x16x32_f16(av, Bf[ks], acc, 0, 0, 0);
            }
            int srow = tile * 16 + kb * 4;
#pragma unroll
            for (int r = 0; r < 4; ++r) {
                int s = srow + r;
                if (m < 5 && s < 676) P2h[m * 676 + s] = (_Float16)acc[r];
            }
        }
    }
    __syncthreads();

    // ---- Phase 3: maxpool2 + transform -> t2 channel-packed records ------
#pragma unroll 1
    for (int i = tid; i < 845; i += 256) {
        int c = i / 169, pp = i % 169;
        int ph = pp / 13, pw = pp % 13;
        const _Float16* q = P2h + c * 676 + (2 * ph) * 26 + 2 * pw;
        h2 a = as_h2(*(const uint_t*)q);
        h2 d = as_h2(*(const uint_t*)(q + 26));
        float mx = fmaxf(fmaxf((float)a[0], (float)a[1]),
                         fmaxf((float)d[0], (float)d[1]));
        write_rec10a(&smemA[pp * 72 + c * 12], mx);
    }
    __syncthreads();

    // ---- Phase 4: conv2 5x5 via MFMA, tap-split (7/6/6/6), part2 stores --
    // Each wave: its taps x 6 M-tiles x 2 MFMA (K=64/tap); B-load amortized
    // over 12 MFMAs; per-wave partials to part2, reduced in 4b.
    {
        int ryb[6];
#pragma unroll
        for (int t = 0; t < 6; ++t) {
            int p = t * 16 + m; p = p > 80 ? 80 : p;        // M-pad: clamp
            ryb[t] = (p / 9) * 13 + (p % 9);
        }
        f32x4 acc[6];
#pragma unroll
        for (int t = 0; t < 6; ++t) { f32x4 z = {0.f,0.f,0.f,0.f}; acc[t] = z; }
#pragma unroll 1
        for (int tap = wv; tap < 25; tap += 4) {
            int di = tap / 5, dj = tap % 5;                 // wave-uniform
            const _Float16* wrow = w2col + nn * 1600 + tap * 64 + kb * 8;
            f16x8 bv0 = *(const f16x8*)(wrow);
            f16x8 bv1 = *(const f16x8*)(wrow + 32);
            int qoff = di * 13 + dj;
#pragma unroll
            for (int t = 0; t < 6; ++t) {
                const _Float16* ab = smemA + (ryb[t] + qoff) * 72 + kb * 8;
                acc[t] = __builtin_amdgcn_mfma_f32_16x16x32_f16(
                             *(const f16x8*)(ab), bv0, acc[t], 0, 0, 0);
                acc[t] = __builtin_amdgcn_mfma_f32_16x16x32_f16(
                             *(const f16x8*)(ab + 32), bv1, acc[t], 0, 0, 0);
            }
        }
        int prow = kb * 4;
#pragma unroll
        for (int t = 0; t < 6; ++t) {
#pragma unroll
            for (int r = 0; r < 4; ++r) {
                int pp = t * 16 + prow + r;
                if (m < 5 && pp < 81) part2[(wv * 5 + m) * 81 + pp] = acc[t][r];
            }
        }
    }
    __syncthreads();

    // ---- Phase 4b: 4-wave reduce -> t3 channel-packed records (t2 dead) --
#pragma unroll 1
    for (int i = tid; i < 405; i += 256) {
        int o = i / 81, pp = i % 81;
        float v = part2[(0 * 5 + o) * 81 + pp] + part2[(1 * 5 + o) * 81 + pp]
                + part2[(2 * 5 + o) * 81 + pp] + part2[(3 * 5 + o) * 81 + pp];
        write_rec10a(&smemA[pp * 72 + o * 12], v);
    }
    __syncthreads();

    // ---- Phase 5: conv3 3x3 via MFMA: M=49 (4 tiles, 1/wave), K=64/tap ---
    // h3h (fp16) aliases part2 (dead after 4b, barrier above).
    {
        int p3 = wv * 16 + m; p3 = p3 > 48 ? 48 : p3;
        int ry3 = (p3 / 7) * 9 + (p3 % 7);
        f32x4 acc = {0.f, 0.f, 0.f, 0.f};
#pragma unroll 1
        for (int tap = 0; tap < 9; ++tap) {
            int di = tap / 3, dj = tap % 3;
            const _Float16* wrow = w3col + nn * 576 + tap * 64 + kb * 8;
            f16x8 bv0 = *(const f16x8*)(wrow);
            f16x8 bv1 = *(const f16x8*)(wrow + 32);
            const _Float16* ab = smemA + (ry3 + di * 9 + dj) * 72 + kb * 8;
            acc = __builtin_amdgcn_mfma_f32_16x16x32_f16(*(const f16x8*)(ab),      bv0, acc, 0, 0, 0);
            acc = __builtin_amdgcn_mfma_f32_16x16x32_f16(*(const f16x8*)(ab + 32), bv1, acc, 0, 0, 0);
        }
#pragma unroll
        for (int r = 0; r < 4; ++r) {
            int pout = wv * 16 + kb * 4 + r;
            if (m < 2 && pout < 49) h3h[m * 49 + pout] = (_Float16)acc[r];
        }
        if (tid == 255) { h3h[98] = (_Float16)0.f; h3h[99] = (_Float16)0.f; }
    }
    __syncthreads();

    // ---- Phase 6: FC [98] -> [200] via uint2 fp16 quads, 2 chains --------
    // fcwQ uint2 (w,o) = cols 4w..4w+3 of W[o]; h3 pair-of-pairs = one b64
    // broadcast. 25 x {dwordx2, ds b64, 2 dot2} vs 49 x {dword, b32, dot2}.
    if (tid < 200) {
        const uint_t* h3u = (const uint_t*)h3h;   // [50] pairs, 8B-aligned
        float a0 = 0.f, a1 = 0.f;
#pragma unroll
        for (int w = 0; w < 25; ++w) {
            uint2 wp = *(const uint2*)(fcwQ + w * 400 + tid * 2);
            uint2 hv = *(const uint2*)(h3u + 2 * w);
            a0 = fdot2f(as_h2(wp.x), as_h2(hv.x), a0);
            a1 = fdot2f(as_h2(wp.y), as_h2(hv.y), a1);
        }
        out[b * 200 + tid] = fcb[tid] + a0 + a1;
    }
}

extern "C" void kernel_launch(void* const* d_in, const int* in_sizes, int n_in,
                              void* d_out, int out_size, void* d_ws, size_t ws_size,
                              hipStream_t stream) {
    const float* x   = (const float*)d_in[0];
    const float* wb1 = (const float*)d_in[1];
    const float* ws1 = (const float*)d_in[2];
    const float* wb2 = (const float*)d_in[3];
    const float* ws2 = (const float*)d_in[4];
    const float* wb3 = (const float*)d_in[5];
    const float* ws3 = (const float*)d_in[6];
    const float* fcw = (const float*)d_in[7];
    const float* fcb = (const float*)d_in[8];
    float* out = (float*)d_out;

    uint_t*   fcwQ  = (uint_t*)((char*)d_ws + FCWQ_BYTE_OFF);
    _Float16* w1col = (_Float16*)((char*)d_ws + W1COL_BYTE_OFF);
    _Float16* w2col = (_Float16*)((char*)d_ws + W2COL_BYTE_OFF);
    _Float16* w3col = (_Float16*)((char*)d_ws + W3COL_BYTE_OFF);

    kan_prep<<<64, 256, 0, stream>>>(wb1, ws1, wb2, ws2, wb3, ws3, fcw,
                                     fcwQ, w1col, w2col, w3col);

    int B = in_sizes[0] / 784;  // 4096
    kan_fused<<<B, 256, 0, stream>>>(x, w1col, w2col, w3col, fcwQ, fcb, out);
}

// Round 16
// 143.067 us; speedup vs baseline: 1.0490x; 1.0490x over previous
//
#include <hip/hip_runtime.h>

// KAN conv feature extractor, fully fused: one workgroup (256 thr) per batch element.
// conv1 3x3 (1->5) + maxpool2 -> conv2 5x5 (5->5) -> conv3 3x3 (5->2) -> FC(98->200)
// All three convs on MFMA (v_mfma_f32_16x16x32_f16). Activation records in LDS;
// K/M-pads always multiply ZERO weight columns against FINITE fp16 data (never 0*Inf).
// R16 = R14 verbatim (best verified: 77.1us fused). R15's further diet (stride-12
// records + uint2 FC) regressed to 84us via VGPR 44->56 / occupancy 47->38 --
// instruction cuts only pay when they leave register pressure and phase structure
// untouched. R14 is the session optimum:
//   - FC as packed-fp16 dot2: fcwP[49][200] u32 pairs, h3 fp16 -> one u32 broadcast
//     per pair; 49 x {dword, b32, dot2} on 200 threads.
//   - conv1: 43 M-tiles, K=160, B-frags in 5 VGPR-pairs; XOR-swizzled t1.
//   - conv2: tap-split (7/6/6/6), K=64/tap channel-packed t2, part2 + 4-wave reduce.
//   - conv3: 4 M-tiles (1/wave), K=64/tap on t3; output direct to fp16 h3h.

typedef _Float16 h2 __attribute__((ext_vector_type(2)));
typedef _Float16 f16x8 __attribute__((ext_vector_type(8)));
typedef float f32x4 __attribute__((ext_vector_type(4)));
typedef unsigned int uint_t;
typedef unsigned long long u64;

__device__ __forceinline__ h2 as_h2(uint_t u) { union { uint_t u; h2 h; } c; c.u = u; return c.h; }
__device__ __forceinline__ uint_t pk(float a, float b) {
    h2 v; v[0] = (_Float16)a; v[1] = (_Float16)b;
    union { h2 h; uint_t u; } c; c.h = v; return c.u;
}

__device__ __forceinline__ float fdot2f(h2 a, h2 b, float c) {
#if __has_builtin(__builtin_amdgcn_fdot2)
    return __builtin_amdgcn_fdot2(a, b, c, false);
#else
    return c + (float)a[0] * (float)b[0] + (float)a[1] * (float)b[1];
#endif
}

__device__ __forceinline__ float silu_f(float v) {
    return v / (1.0f + __expf(-v));
}

// Record words for value v: halves [silu, b0..b7, 0] as R0(4h), R1(4h), R2(2h).
// Uniform-knot cubic B-spline, grid[j] = (j-3)*0.4 - 1; only 4 bases nonzero:
// cell c = floor((v+2.2)/0.4), u = frac; bases j=c-3..c get
// {(1-u)^3, 3u^3-6u^2+4, -3u^3+3u^2+3u+1, u^3}/6 (branchless 128-bit funnel shift).
struct RecW { u64 R0, R1; uint_t R2; };
__device__ __forceinline__ RecW rec_words(float v) {
    float s  = silu_f(v);
    float t  = (v + 2.2f) * 2.5f;
    float cf = floorf(t);
    int   c  = (int)cf;
    float u  = t - cf;
    float u2 = u * u, u3 = u2 * u;
    float w  = 1.0f - u;
    const float k6 = 0.16666667f;
    float n0 = k6 * u3;
    float n1 = k6 * (-3.0f * u3 + 3.0f * u2 + 3.0f * u + 1.0f);
    float n2 = k6 * (3.0f * u3 - 6.0f * u2 + 4.0f);
    float n3 = k6 * (w * w * w);
    u64 H = ((u64)pk(n1, n0) << 32) | (u64)pk(n3, n2);   // halves [n3,n2,n1,n0]
    if ((unsigned)c > 10u) H = 0;                        // outside [-2.2,2.2): zero bases
    int cc = c < 0 ? 0 : (c > 10 ? 10 : c);
    int L  = cc * 16 - 48;                               // window shift, mult of 16
    u64 sl_lo = (L < 64) ? (H << (L & 63)) : 0;
    u64 hi_a  = (L == 0) ? 0 : (H >> ((64 - L) & 63));
    u64 hi_b  = H << ((L - 64) & 63);
    u64 sl_hi = (L < 64) ? hi_a : hi_b;
    u64 sr    = H >> ((-L) & 63);
    u64 B0 = (L >= 0) ? sl_lo : sr;                      // window halves 0..3
    u64 B1 = (L >= 0) ? sl_hi : 0;                       // window halves 4..7
    RecW r;
    r.R0 = (B0 << 16) | (u64)pk(s, 0.0f);                // [silu, b0, b1, b2]
    r.R1 = (B0 >> 48) | (B1 << 16);                      // [b3, b4, b5, b6]
    r.R2 = (uint_t)(B1 >> 48);                           // [b7, 0]
    return r;
}

// 16-half record with XOR-swizzled 16B chunks (t1).
__device__ __forceinline__ void write_rec16s(_Float16* p, int off, float v) {
    RecW rw = rec_words(v);
    uint4 lo, hi;
    lo.x = (uint_t)rw.R0; lo.y = (uint_t)(rw.R0 >> 32);
    lo.z = (uint_t)rw.R1; lo.w = (uint_t)(rw.R1 >> 32);
    hi.x = rw.R2; hi.y = 0; hi.z = 0; hi.w = 0;
    *(uint4*)(p + off)       = lo;                       // halves 0-7
    *(uint4*)(p + (8 ^ off)) = hi;                       // halves 8-15
}

// 10-half packed record (channel-packed K for conv2/conv3): 5 dword stores.
__device__ __forceinline__ void write_rec10(_Float16* p, float v) {
    RecW rw = rec_words(v);
    uint_t* d = (uint_t*)p;
    d[0] = (uint_t)rw.R0; d[1] = (uint_t)(rw.R0 >> 32);
    d[2] = (uint_t)rw.R1; d[3] = (uint_t)(rw.R1 >> 32);
    d[4] = rw.R2;
}

// d_ws layout (bytes):
//   [0)      fcwP : u32 [49][200] FC weight pairs: fcwP[q*200+o] = pk(W[o][2q], W[o][2q+1])
//   [39200)  w1col: fp16 [6][160]  conv1 K-major cols (col5 zero; 10 recs x 16h,
//                                  rec t<9, f<9 real; else 0)
//   [41120)  w2col: fp16 [6][1600] conv2 tap-major cols [tap(di*5+dj)][64h]:
//                                  k -> (c=k/10, f=k%10); k>=50 or f==9 -> 0
//   [60320)  w3col: fp16 [6][576]  conv3 tap-major cols [tap(di*3+dj)][64h], cols 2-5 zero
#define FCWP_BYTE_OFF   0
#define W1COL_BYTE_OFF  39200
#define W2COL_BYTE_OFF  41120
#define W3COL_BYTE_OFF  60320

__global__ __launch_bounds__(256) void kan_prep(
    const float* __restrict__ wb1, const float* __restrict__ ws1,
    const float* __restrict__ wb2, const float* __restrict__ ws2,
    const float* __restrict__ wb3, const float* __restrict__ ws3,
    const float* __restrict__ fcw, uint_t* __restrict__ fcwP,
    _Float16* __restrict__ w1col, _Float16* __restrict__ w2col,
    _Float16* __restrict__ w3col)
{
    int gtid = blockIdx.x * 256 + threadIdx.x;
    int gstr = gridDim.x * 256;
    for (int i = gtid; i < 9800; i += gstr) {         // fcwP [49][200]
        int q = i / 200, o = i % 200;
        fcwP[i] = pk(fcw[o * 98 + 2 * q], fcw[o * 98 + 2 * q + 1]);
    }
    for (int i = gtid; i < 960; i += gstr) {          // w1col [6][160]
        int n = i / 160, k = i % 160;
        int rec = k >> 4, f = k & 15;
        float v = 0.f;
        if (n < 5 && rec < 9 && f < 9)
            v = (f == 0) ? wb1[n * 9 + rec] : ws1[(n * 9 + rec) * 8 + (f - 1)];
        w1col[i] = (_Float16)v;
    }
    for (int i = gtid; i < 9600; i += gstr) {         // w2col [6][1600]
        int n = i / 1600, k2 = i % 1600;
        int tap = k2 >> 6, k = k2 & 63;
        int di = tap / 5, dj = tap % 5;
        int c = k / 10, f = k % 10;
        float v = 0.f;
        if (n < 5 && k < 50 && f < 9) {
            int r = n * 125 + c * 25 + di * 5 + dj;
            v = (f == 0) ? wb2[r] : ws2[r * 8 + (f - 1)];
        }
        w2col[i] = (_Float16)v;
    }
    for (int i = gtid; i < 3456; i += gstr) {         // w3col [6][576]
        int n = i / 576, k2 = i % 576;
        int tap = k2 >> 6, k = k2 & 63;
        int di = tap / 3, dj = tap % 3;
        int c = k / 10, f = k % 10;
        float v = 0.f;
        if (n < 2 && k < 50 && f < 9) {
            int r = n * 45 + c * 9 + di * 3 + dj;
            v = (f == 0) ? wb3[r] : ws3[r * 8 + (f - 1)];
        }
        w3col[i] = (_Float16)v;
    }
}

// LDS (overlaid in time):
//   smemA fp16[12544]: t1 [784][16] (XOR-swizzled chunks) = 12544h
//                    | t2 [169 pos][72] (5c x 10h @ 0..49, pad 50..71) = 12168h
//                    | t3 [81 pos][72] (channel-packed, reuses t2 addresses)
//   smemB f32[1696]:   P2h fp16 [5][676] = 1690f | part2 [4w][5o][81] = 1620f
//                    | h3h fp16 [98] (aliases part2 base; part2 dead after 4b)
// Total 31872 B -> 5 WG/CU (20 waves).
__global__ __launch_bounds__(256) void kan_fused(
    const float* __restrict__ x,        // [B,1,28,28]
    const _Float16* __restrict__ w1col, // [6][160]
    const _Float16* __restrict__ w2col, // [6][1600]
    const _Float16* __restrict__ w3col, // [6][576]
    const uint_t* __restrict__ fcwP,    // [49][200] u32 pairs
    const float* __restrict__ fcb,      // [200]
    float* __restrict__ out)            // [B,200]
{
    __shared__ __align__(16) _Float16 smemA[12544];
    __shared__ __align__(16) float    smemB[1696];
    _Float16* P2h   = (_Float16*)smemB;  // [c][676] halves
    float*    part2 = smemB;             // [(w*5+o)*81 + pp]
    _Float16* h3h   = (_Float16*)smemB;  // [98] fp16 (after 4b)

    const int b   = blockIdx.x;
    const int tid = threadIdx.x;
    const int wv  = __builtin_amdgcn_readfirstlane(tid >> 6);  // wave id 0..3
    const int ln  = tid & 63;

    // MFMA lane decomposition
    const int m   = ln & 15;        // A row (position); C col (out ch)
    const int kb  = ln >> 4;        // k-block: lane k = kb*8 + j
    const int hr  = kb >> 1;        // conv1: record within kstep pair
    const int s8  = (kb & 1) * 8;   // conv1: half offset within record
    const int nn  = m < 5 ? m : 5;  // B column (col 5 = zeros)

    // ---- Phase 1: transform input pixels -> t1 records (swizzled) --------
#pragma unroll 1
    for (int i = tid; i < 784; i += 256)
        write_rec16s(&smemA[i * 16], (i & 4) << 1, x[b * 784 + i]);
    __syncthreads();

    // ---- Phase 2: conv1 3x3 via MFMA: M=676 (43 tiles), N=5(->16), K=160 -
    {
        f16x8 Bf[5];
#pragma unroll
        for (int ks = 0; ks < 5; ++ks)
            Bf[ks] = *(const f16x8*)(w1col + nn * 160 + ks * 32 + kb * 8);
        const int dpix[10] = {0, 1, 2, 28, 29, 30, 56, 57, 58, 0};
#pragma unroll 1
        for (int tile = wv; tile < 43; tile += 4) {
            int p = tile * 16 + m; p = p > 675 ? 675 : p;   // M-pad: clamp (finite A)
            int pix0 = (p / 26) * 28 + (p % 26);
            f32x4 acc = {0.f, 0.f, 0.f, 0.f};
#pragma unroll
            for (int ks = 0; ks < 5; ++ks) {
                int dp = hr ? dpix[2 * ks + 1] : dpix[2 * ks];
                int p2 = pix0 + dp;
                int addr = p2 * 16 + (s8 ^ ((p2 & 4) << 1));   // match writer swizzle
                f16x8 av = *(const f16x8*)(smemA + addr);
                acc = __builtin_amdgcn_mfma_f32_16x16x32_f16(av, Bf[ks], acc, 0, 0, 0);
            }
            int srow = tile * 16 + kb * 4;
#pragma unroll
            for (int r = 0; r < 4; ++r) {
                int s = srow + r;
                if (m < 5 && s < 676) P2h[m * 676 + s] = (_Float16)acc[r];
            }
        }
    }
    __syncthreads();

    // ---- Phase 3: maxpool2 + transform -> t2 channel-packed records ------
#pragma unroll 1
    for (int i = tid; i < 845; i += 256) {
        int c = i / 169, pp = i % 169;
        int ph = pp / 13, pw = pp % 13;
        const _Float16* q = P2h + c * 676 + (2 * ph) * 26 + 2 * pw;
        h2 a = as_h2(*(const uint_t*)q);
        h2 d = as_h2(*(const uint_t*)(q + 26));
        float mx = fmaxf(fmaxf((float)a[0], (float)a[1]),
                         fmaxf((float)d[0], (float)d[1]));
        write_rec10(&smemA[pp * 72 + c * 10], mx);
    }
    __syncthreads();

    // ---- Phase 4: conv2 5x5 via MFMA, tap-split (7/6/6/6), part2 stores --
    // Each wave: its taps x 6 M-tiles x 2 MFMA (K=64/tap); B-load amortized
    // over 12 MFMAs; per-wave partials to part2, reduced in 4b.
    {
        int ryb[6];
#pragma unroll
        for (int t = 0; t < 6; ++t) {
            int p = t * 16 + m; p = p > 80 ? 80 : p;        // M-pad: clamp
            ryb[t] = (p / 9) * 13 + (p % 9);
        }
        f32x4 acc[6];
#pragma unroll
        for (int t = 0; t < 6; ++t) { f32x4 z = {0.f,0.f,0.f,0.f}; acc[t] = z; }
#pragma unroll 1
        for (int tap = wv; tap < 25; tap += 4) {
            int di = tap / 5, dj = tap % 5;                 // wave-uniform
            const _Float16* wrow = w2col + nn * 1600 + tap * 64 + kb * 8;
            f16x8 bv0 = *(const f16x8*)(wrow);
            f16x8 bv1 = *(const f16x8*)(wrow + 32);
            int qoff = di * 13 + dj;
#pragma unroll
            for (int t = 0; t < 6; ++t) {
                const _Float16* ab = smemA + (ryb[t] + qoff) * 72 + kb * 8;
                acc[t] = __builtin_amdgcn_mfma_f32_16x16x32_f16(
                             *(const f16x8*)(ab), bv0, acc[t], 0, 0, 0);
                acc[t] = __builtin_amdgcn_mfma_f32_16x16x32_f16(
                             *(const f16x8*)(ab + 32), bv1, acc[t], 0, 0, 0);
            }
        }
        int prow = kb * 4;
#pragma unroll
        for (int t = 0; t < 6; ++t) {
#pragma unroll
            for (int r = 0; r < 4; ++r) {
                int pp = t * 16 + prow + r;
                if (m < 5 && pp < 81) part2[(wv * 5 + m) * 81 + pp] = acc[t][r];
            }
        }
    }
    __syncthreads();

    // ---- Phase 4b: 4-wave reduce -> t3 channel-packed records (t2 dead) --
#pragma unroll 1
    for (int i = tid; i < 405; i += 256) {
        int o = i / 81, pp = i % 81;
        float v = part2[(0 * 5 + o) * 81 + pp] + part2[(1 * 5 + o) * 81 + pp]
                + part2[(2 * 5 + o) * 81 + pp] + part2[(3 * 5 + o) * 81 + pp];
        write_rec10(&smemA[pp * 72 + o * 10], v);
    }
    __syncthreads();

    // ---- Phase 5: conv3 3x3 via MFMA: M=49 (4 tiles, 1/wave), K=64/tap ---
    // h3h (fp16) aliases part2 (dead after 4b, barrier above).
    {
        int p3 = wv * 16 + m; p3 = p3 > 48 ? 48 : p3;
        int ry3 = (p3 / 7) * 9 + (p3 % 7);
        f32x4 acc = {0.f, 0.f, 0.f, 0.f};
#pragma unroll 1
        for (int tap = 0; tap < 9; ++tap) {
            int di = tap / 3, dj = tap % 3;
            const _Float16* wrow = w3col + nn * 576 + tap * 64 + kb * 8;
            f16x8 bv0 = *(const f16x8*)(wrow);
            f16x8 bv1 = *(const f16x8*)(wrow + 32);
            const _Float16* ab = smemA + (ry3 + di * 9 + dj) * 72 + kb * 8;
            acc = __builtin_amdgcn_mfma_f32_16x16x32_f16(*(const f16x8*)(ab),      bv0, acc, 0, 0, 0);
            acc = __builtin_amdgcn_mfma_f32_16x16x32_f16(*(const f16x8*)(ab + 32), bv1, acc, 0, 0, 0);
        }
#pragma unroll
        for (int r = 0; r < 4; ++r) {
            int pout = wv * 16 + kb * 4 + r;
            if (m < 2 && pout < 49) h3h[m * 49 + pout] = (_Float16)acc[r];
        }
    }
    __syncthreads();

    // ---- Phase 6: FC [98] -> [200] via packed fp16 dot2, 2 chains --------
    // fcwP[q*200+o] = (W[o][2q], W[o][2q+1]); h3h pair (2q,2q+1) = one u32
    // broadcast read. 49 dot2 per thread vs 98 fma + 98 cvt before.
    if (tid < 200) {
        const uint_t* h3u = (const uint_t*)h3h;   // [49] pairs, 4B-aligned
        float a0 = 0.f, a1 = 0.f;
#pragma unroll 8
        for (int q = 0; q < 48; q += 2) {
            a0 = fdot2f(as_h2(fcwP[q * 200 + tid]),       as_h2(h3u[q]),     a0);
            a1 = fdot2f(as_h2(fcwP[(q + 1) * 200 + tid]), as_h2(h3u[q + 1]), a1);
        }
        a0 = fdot2f(as_h2(fcwP[48 * 200 + tid]), as_h2(h3u[48]), a0);  // q=48
        out[b * 200 + tid] = fcb[tid] + a0 + a1;
    }
}

extern "C" void kernel_launch(void* const* d_in, const int* in_sizes, int n_in,
                              void* d_out, int out_size, void* d_ws, size_t ws_size,
                              hipStream_t stream) {
    const float* x   = (const float*)d_in[0];
    const float* wb1 = (const float*)d_in[1];
    const float* ws1 = (const float*)d_in[2];
    const float* wb2 = (const float*)d_in[3];
    const float* ws2 = (const float*)d_in[4];
    const float* wb3 = (const float*)d_in[5];
    const float* ws3 = (const float*)d_in[6];
    const float* fcw = (const float*)d_in[7];
    const float* fcb = (const float*)d_in[8];
    float* out = (float*)d_out;

    uint_t*   fcwP  = (uint_t*)((char*)d_ws + FCWP_BYTE_OFF);
    _Float16* w1col = (_Float16*)((char*)d_ws + W1COL_BYTE_OFF);
    _Float16* w2col = (_Float16*)((char*)d_ws + W2COL_BYTE_OFF);
    _Float16* w3col = (_Float16*)((char*)d_ws + W3COL_BYTE_OFF);

    kan_prep<<<32, 256, 0, stream>>>(wb1, ws1, wb2, ws2, wb3, ws3, fcw,
                                     fcwP, w1col, w2col, w3col);

    int B = in_sizes[0] / 784;  // 4096
    kan_fused<<<B, 256, 0, stream>>>(x, w1col, w2col, w3col, fcwP, fcb, out);
}